// Round 1
// baseline (287.355 us; speedup 1.0000x reference)
//
#include <hip/hip_runtime.h>
#include <hip/hip_bf16.h>

#define EMB 256
#define HEADS 4
#define HD 64
#define NTOK 4096

typedef __attribute__((ext_vector_type(8))) short bf16x8;
typedef __attribute__((ext_vector_type(4))) float f32x4;

#define MFMA16(a, b, c) __builtin_amdgcn_mfma_f32_16x16x32_bf16(a, b, c, 0, 0, 0)

static __device__ __forceinline__ ushort f2bf(float f) {
    __hip_bfloat16 h = __float2bfloat16(f);
    return *(ushort*)&h;
}

// ---------------- f32 -> bf16 conversion ----------------
__global__ void cvtAB(const float* __restrict__ A, const float* __restrict__ B,
                      ushort* __restrict__ Ao, ushort* __restrict__ Bo) {
    const float* s = blockIdx.y ? B : A;
    ushort* d = blockIdx.y ? Bo : Ao;
    int i = (blockIdx.x * 256 + threadIdx.x) * 4;
    float4 v = *(const float4*)(s + i);
    ushort4 o;
    o.x = f2bf(v.x); o.y = f2bf(v.y); o.z = f2bf(v.z); o.w = f2bf(v.w);
    *(ushort4*)(d + i) = o;
}

__global__ void cvtW(const float* __restrict__ Wq, const float* __restrict__ Wk,
                     const float* __restrict__ Wv, const float* __restrict__ Wo,
                     ushort* __restrict__ Wall) {
    const float* s = (blockIdx.y == 0) ? Wq : (blockIdx.y == 1) ? Wk : (blockIdx.y == 2) ? Wv : Wo;
    ushort* d = Wall + (size_t)blockIdx.y * 65536;
    int i = (blockIdx.x * 256 + threadIdx.x) * 4;
    float4 v = *(const float4*)(s + i);
    ushort4 o;
    o.x = f2bf(v.x); o.y = f2bf(v.y); o.z = f2bf(v.z); o.w = f2bf(v.w);
    *(ushort4*)(d + i) = o;
}

// ---------------- QKV projection: out = X @ W^T (bf16 MFMA) ----------------
// z=0: Q output [m][256], pre-scaled by 1/8
// z=1: K output [m][256]
// z=2: V output transposed per head: Vt[h][d][m]
__global__ __launch_bounds__(256) void qkv_proj(const ushort* __restrict__ X,
                                                const ushort* __restrict__ Wall,
                                                ushort* __restrict__ Qo,
                                                ushort* __restrict__ Ko,
                                                ushort* __restrict__ Vto) {
    int w = threadIdx.x >> 6, lane = threadIdx.x & 63;
    int lr = lane & 15, lg = lane >> 4;
    int z = blockIdx.z;
    const ushort* W = Wall + (size_t)z * 65536;
    int rbase = blockIdx.x * 64 + w * 16;
    int cbase = blockIdx.y * 64;

    f32x4 acc[4] = {};
#pragma unroll
    for (int kk = 0; kk < 256; kk += 32) {
        bf16x8 a = *(const bf16x8*)(X + (size_t)(rbase + lr) * EMB + kk + lg * 8);
#pragma unroll
        for (int cj = 0; cj < 4; ++cj) {
            bf16x8 b = *(const bf16x8*)(W + (size_t)(cbase + cj * 16 + lr) * EMB + kk + lg * 8);
            acc[cj] = MFMA16(a, b, acc[cj]);
        }
    }
#pragma unroll
    for (int cj = 0; cj < 4; ++cj)
#pragma unroll
        for (int j = 0; j < 4; ++j) {
            int R = rbase + lg * 4 + j;
            int col = cbase + cj * 16 + lr;
            float v = acc[cj][j];
            if (z == 0) {
                Qo[(size_t)R * EMB + col] = f2bf(v * 0.125f);  // fold 1/sqrt(64)
            } else if (z == 1) {
                Ko[(size_t)R * EMB + col] = f2bf(v);
            } else {
                int h = col >> 6, d = col & 63;
                Vto[(size_t)h * HD * NTOK + (size_t)d * NTOK + R] = f2bf(v);
            }
        }
}

// ---------------- flash cross-attention ----------------
// grid: (NTOK/64, HEADS); block 256 (4 waves); each wave owns 16 q-rows
__global__ __launch_bounds__(256) void attn(const ushort* __restrict__ Q,
                                            const ushort* __restrict__ K,
                                            const ushort* __restrict__ Vt,
                                            ushort* __restrict__ Ctx) {
    __shared__ ushort lK[64 * 64];
    __shared__ ushort lV[64 * 64];
    __shared__ ushort lP[4 * 16 * 64];

    int w = threadIdx.x >> 6, lane = threadIdx.x & 63;
    int lr = lane & 15, lg = lane >> 4;
    int qbase = blockIdx.x * 64;
    int head = blockIdx.y;
    const ushort* Vth = Vt + (size_t)head * HD * NTOK;

    // Q fragments held in registers for whole kernel (already includes 1/8 scale)
    const ushort* qrow = Q + (size_t)(qbase + w * 16 + lr) * EMB + head * HD + lg * 8;
    bf16x8 q0 = *(const bf16x8*)(qrow);
    bf16x8 q1 = *(const bf16x8*)(qrow + 32);

    float m[4], ls[4];
    f32x4 oacc[4] = {};
#pragma unroll
    for (int j = 0; j < 4; ++j) { m[j] = -1e30f; ls[j] = 0.0f; }

    ushort* lPw = lP + w * 1024;

    for (int kv = 0; kv < NTOK; kv += 64) {
        __syncthreads();
        // stage K[kv..kv+63][head*64..+63] -> lK[64][64]; Vt[h][0..63][kv..+63] -> lV[64][64]
#pragma unroll
        for (int i = 0; i < 2; ++i) {
            int c = threadIdx.x + i * 256;  // 0..511 chunks of 16B
            int row = c >> 3, seg = c & 7;
            *(uint4*)(&lK[row * 64 + seg * 8]) =
                *(const uint4*)(K + (size_t)(kv + row) * EMB + head * HD + seg * 8);
            *(uint4*)(&lV[row * 64 + seg * 8]) =
                *(const uint4*)(Vth + (size_t)row * NTOK + kv + seg * 8);
        }
        __syncthreads();

        // scores: 16 q-rows x 64 k-cols per wave
        f32x4 s[4];
#pragma unroll
        for (int kj = 0; kj < 4; ++kj) {
            const ushort* kb = &lK[(kj * 16 + lr) * 64 + lg * 8];
            bf16x8 b0 = *(const bf16x8*)(kb);
            bf16x8 b1 = *(const bf16x8*)(kb + 32);
            f32x4 acc = {};
            acc = MFMA16(q0, b0, acc);
            acc = MFMA16(q1, b1, acc);
            s[kj] = acc;
        }

        // online softmax (rows j: lane covers row lg*4+j, col kj*16+lr)
        float pexp[4][4];
#pragma unroll
        for (int j = 0; j < 4; ++j) {
            float tm = fmaxf(fmaxf(s[0][j], s[1][j]), fmaxf(s[2][j], s[3][j]));
#pragma unroll
            for (int off = 1; off < 16; off <<= 1) tm = fmaxf(tm, __shfl_xor(tm, off));
            float mn = fmaxf(m[j], tm);
            float sc = __expf(m[j] - mn);
            float rs = 0.0f;
#pragma unroll
            for (int kj = 0; kj < 4; ++kj) {
                float e = __expf(s[kj][j] - mn);
                pexp[kj][j] = e;
                rs += e;
            }
#pragma unroll
            for (int off = 1; off < 16; off <<= 1) rs += __shfl_xor(rs, off);
            ls[j] = ls[j] * sc + rs;
            m[j] = mn;
#pragma unroll
            for (int dblk = 0; dblk < 4; ++dblk) oacc[dblk][j] *= sc;
        }

        // P -> per-wave LDS (bf16), then re-fragment for PV
#pragma unroll
        for (int kj = 0; kj < 4; ++kj)
#pragma unroll
            for (int j = 0; j < 4; ++j)
                lPw[(lg * 4 + j) * 64 + kj * 16 + lr] = f2bf(pexp[kj][j]);

        bf16x8 pa0 = *(const bf16x8*)(&lPw[lr * 64 + lg * 8]);
        bf16x8 pa1 = *(const bf16x8*)(&lPw[lr * 64 + 32 + lg * 8]);
#pragma unroll
        for (int dblk = 0; dblk < 4; ++dblk) {
            const ushort* vb = &lV[(dblk * 16 + lr) * 64 + lg * 8];
            bf16x8 v0 = *(const bf16x8*)(vb);
            bf16x8 v1 = *(const bf16x8*)(vb + 32);
            oacc[dblk] = MFMA16(pa0, v0, oacc[dblk]);
            oacc[dblk] = MFMA16(pa1, v1, oacc[dblk]);
        }
    }

    float inv[4];
#pragma unroll
    for (int j = 0; j < 4; ++j) inv[j] = 1.0f / ls[j];
#pragma unroll
    for (int dblk = 0; dblk < 4; ++dblk)
#pragma unroll
        for (int j = 0; j < 4; ++j) {
            int R = qbase + w * 16 + lg * 4 + j;
            int col = head * HD + dblk * 16 + lr;
            Ctx[(size_t)R * EMB + col] = f2bf(oacc[dblk][j] * inv[j]);
        }
}

// ---------------- output projection: out = Ctx @ Wo^T + bo + X ----------------
__global__ __launch_bounds__(256) void out_proj(const ushort* __restrict__ Ctx,
                                                const ushort* __restrict__ Wo,
                                                const float* __restrict__ bo,
                                                const float* __restrict__ X,
                                                float* __restrict__ out) {
    int w = threadIdx.x >> 6, lane = threadIdx.x & 63;
    int lr = lane & 15, lg = lane >> 4;
    int rbase = blockIdx.x * 64 + w * 16;
    int cbase = blockIdx.y * 64;

    f32x4 acc[4] = {};
#pragma unroll
    for (int kk = 0; kk < 256; kk += 32) {
        bf16x8 a = *(const bf16x8*)(Ctx + (size_t)(rbase + lr) * EMB + kk + lg * 8);
#pragma unroll
        for (int cj = 0; cj < 4; ++cj) {
            bf16x8 b = *(const bf16x8*)(Wo + (size_t)(cbase + cj * 16 + lr) * EMB + kk + lg * 8);
            acc[cj] = MFMA16(a, b, acc[cj]);
        }
    }
#pragma unroll
    for (int cj = 0; cj < 4; ++cj)
#pragma unroll
        for (int j = 0; j < 4; ++j) {
            int R = rbase + lg * 4 + j;
            int col = cbase + cj * 16 + lr;
            out[(size_t)R * EMB + col] = acc[cj][j] + bo[col] + X[(size_t)R * EMB + col];
        }
}

extern "C" void kernel_launch(void* const* d_in, const int* in_sizes, int n_in,
                              void* d_out, int out_size, void* d_ws, size_t ws_size,
                              hipStream_t stream) {
    const float* A  = (const float*)d_in[0];
    const float* B  = (const float*)d_in[1];
    const float* Wq = (const float*)d_in[2];
    const float* Wk = (const float*)d_in[3];
    const float* Wv = (const float*)d_in[4];
    const float* Wo = (const float*)d_in[5];
    const float* bo = (const float*)d_in[6];
    float* out = (float*)d_out;

    ushort* ws = (ushort*)d_ws;
    const size_t TE = (size_t)NTOK * EMB;  // 1048576 elements
    ushort* wall = ws;                 // 4 * 65536
    ushort* abf = wall + 4 * 65536;
    ushort* bbf = abf + TE;
    ushort* q0  = bbf + TE;
    ushort* q1  = q0 + TE;
    ushort* k0  = q1 + TE;
    ushort* k1  = k0 + TE;
    ushort* vt0 = k1 + TE;
    ushort* vt1 = vt0 + TE;
    ushort* c0  = vt1 + TE;
    ushort* c1  = c0 + TE;

    cvtAB<<<dim3(1024, 2), 256, 0, stream>>>(A, B, abf, bbf);
    cvtW<<<dim3(64, 4), 256, 0, stream>>>(Wq, Wk, Wv, Wo, wall);

    // A produces: Q(dir0), K(dir1), V(dir1);  B produces: Q(dir1), K(dir0), V(dir0)
    qkv_proj<<<dim3(64, 4, 3), 256, 0, stream>>>(abf, wall, q0, k1, vt1);
    qkv_proj<<<dim3(64, 4, 3), 256, 0, stream>>>(bbf, wall, q1, k0, vt0);

    attn<<<dim3(64, HEADS), 256, 0, stream>>>(q0, k0, vt0, c0);
    attn<<<dim3(64, HEADS), 256, 0, stream>>>(q1, k1, vt1, c1);

    out_proj<<<dim3(64, 4), 256, 0, stream>>>(c0, wall + 3 * 65536, bo, A, out);
    out_proj<<<dim3(64, 4), 256, 0, stream>>>(c1, wall + 3 * 65536, bo, B, out + TE);
}

// Round 2
// 187.117 us; speedup vs baseline: 1.5357x; 1.5357x over previous
//
#include <hip/hip_runtime.h>
#include <hip/hip_bf16.h>
#include <math.h>

#define EMB 256
#define HEADS 4
#define HD 64
#define NTOK 4096

typedef __attribute__((ext_vector_type(8))) short bf16x8;
typedef __attribute__((ext_vector_type(4))) float f32x4;

#define MFMA16(a, b, c) __builtin_amdgcn_mfma_f32_16x16x32_bf16(a, b, c, 0, 0, 0)

static __device__ __forceinline__ ushort f2bf(float f) {
    __hip_bfloat16 h = __float2bfloat16(f);
    return *(ushort*)&h;
}

// ---------------- f32 -> bf16 conversion ----------------
__global__ void cvtAB(const float* __restrict__ A, const float* __restrict__ B,
                      ushort* __restrict__ Ao, ushort* __restrict__ Bo) {
    const float* s = blockIdx.y ? B : A;
    ushort* d = blockIdx.y ? Bo : Ao;
    int i = (blockIdx.x * 256 + threadIdx.x) * 4;
    float4 v = *(const float4*)(s + i);
    ushort4 o;
    o.x = f2bf(v.x); o.y = f2bf(v.y); o.z = f2bf(v.z); o.w = f2bf(v.w);
    *(ushort4*)(d + i) = o;
}

__global__ void cvtW(const float* __restrict__ Wq, const float* __restrict__ Wk,
                     const float* __restrict__ Wv, const float* __restrict__ Wo,
                     ushort* __restrict__ Wall) {
    const float* s = (blockIdx.y == 0) ? Wq : (blockIdx.y == 1) ? Wk : (blockIdx.y == 2) ? Wv : Wo;
    ushort* d = Wall + (size_t)blockIdx.y * 65536;
    int i = (blockIdx.x * 256 + threadIdx.x) * 4;
    float4 v = *(const float4*)(s + i);
    ushort4 o;
    o.x = f2bf(v.x); o.y = f2bf(v.y); o.z = f2bf(v.z); o.w = f2bf(v.w);
    *(ushort4*)(d + i) = o;
}

// ---------------- QKV projection: out = X @ W^T (bf16 MFMA) ----------------
// kind=0: Q output [m][256], pre-scaled by log2(e)/8 (exp2 softmax domain)
// kind=1: K output [m][256]
// kind=2: V output transposed per head: Vt[h][d][m]
__global__ __launch_bounds__(256) void qkv_proj(const ushort* __restrict__ Xa,
                                                const ushort* __restrict__ Xb,
                                                const ushort* __restrict__ Wall,
                                                ushort* __restrict__ Q0, ushort* __restrict__ K1, ushort* __restrict__ Vt1,
                                                ushort* __restrict__ Q1, ushort* __restrict__ K0, ushort* __restrict__ Vt0) {
    int w = threadIdx.x >> 6, lane = threadIdx.x & 63;
    int lr = lane & 15, lg = lane >> 4;
    int z = blockIdx.z;
    int kind = (z < 3) ? z : z - 3;
    const ushort* X = (z < 3) ? Xa : Xb;
    ushort* Qo = (z < 3) ? Q0 : Q1;
    ushort* Ko = (z < 3) ? K1 : K0;
    ushort* Vto = (z < 3) ? Vt1 : Vt0;
    const ushort* W = Wall + (size_t)kind * 65536;
    int rbase = blockIdx.x * 64 + w * 16;
    int cbase = blockIdx.y * 64;

    f32x4 acc[4] = {};
#pragma unroll
    for (int kk = 0; kk < 256; kk += 32) {
        bf16x8 a = *(const bf16x8*)(X + (size_t)(rbase + lr) * EMB + kk + lg * 8);
#pragma unroll
        for (int cj = 0; cj < 4; ++cj) {
            bf16x8 b = *(const bf16x8*)(W + (size_t)(cbase + cj * 16 + lr) * EMB + kk + lg * 8);
            acc[cj] = MFMA16(a, b, acc[cj]);
        }
    }
    const float QS = 0.125f * 1.4426950408889634f;  // 1/sqrt(64) * log2(e)
#pragma unroll
    for (int cj = 0; cj < 4; ++cj)
#pragma unroll
        for (int j = 0; j < 4; ++j) {
            int R = rbase + lg * 4 + j;
            int col = cbase + cj * 16 + lr;
            float v = acc[cj][j];
            if (kind == 0) {
                Qo[(size_t)R * EMB + col] = f2bf(v * QS);
            } else if (kind == 1) {
                Ko[(size_t)R * EMB + col] = f2bf(v);
            } else {
                int h = col >> 6, d = col & 63;
                Vto[(size_t)h * HD * NTOK + (size_t)d * NTOK + R] = f2bf(v);
            }
        }
}

// ---------------- flash cross-attention, both directions ----------------
// grid: (NTOK/64, HEADS, 2); block 256 (4 waves); each wave owns 16 q-rows
// LDS tiles XOR-swizzled: 16B slot s of row r lives at slot (s ^ (r&7)).
__global__ __launch_bounds__(256) void attn(const ushort* __restrict__ Q0,
                                            const ushort* __restrict__ K0,
                                            const ushort* __restrict__ Vt0,
                                            ushort* __restrict__ C0,
                                            const ushort* __restrict__ Q1,
                                            const ushort* __restrict__ K1,
                                            const ushort* __restrict__ Vt1,
                                            ushort* __restrict__ C1) {
    __shared__ ushort lK[64 * 64];
    __shared__ ushort lV[64 * 64];
    __shared__ ushort lP[4 * 16 * 64];

    int dir = blockIdx.z;
    const ushort* Q = dir ? Q1 : Q0;
    const ushort* K = dir ? K1 : K0;
    const ushort* Vt = dir ? Vt1 : Vt0;
    ushort* Ctx = dir ? C1 : C0;

    int w = threadIdx.x >> 6, lane = threadIdx.x & 63;
    int lr = lane & 15, lg = lane >> 4;
    int qbase = blockIdx.x * 64;
    int head = blockIdx.y;
    const ushort* Vth = Vt + (size_t)head * HD * NTOK;

    // staging geometry: thread covers 16B chunks (row, seg) and (row+32, seg)
    int srow = threadIdx.x >> 3, sseg = threadIdx.x & 7;
    int ssw0 = (sseg ^ (srow & 7)) * 8;
    int ssw1 = (sseg ^ ((srow + 32) & 7)) * 8;

    // Q fragments in registers for whole kernel (include log2e/8 scale)
    const ushort* qrow = Q + (size_t)(qbase + w * 16 + lr) * EMB + head * HD + lg * 8;
    bf16x8 q0 = *(const bf16x8*)(qrow);
    bf16x8 q1 = *(const bf16x8*)(qrow + 32);

    float m[4], ls[4];
    f32x4 oacc[4] = {};
#pragma unroll
    for (int j = 0; j < 4; ++j) { m[j] = -1e30f; ls[j] = 0.0f; }

    ushort* lPw = lP + w * 1024;

    // prefetch tile 0 into registers
    uint4 rk0 = *(const uint4*)(K + (size_t)(srow) * EMB + head * HD + sseg * 8);
    uint4 rk1 = *(const uint4*)(K + (size_t)(srow + 32) * EMB + head * HD + sseg * 8);
    uint4 rv0 = *(const uint4*)(Vth + (size_t)srow * NTOK + 0 + sseg * 8);
    uint4 rv1 = *(const uint4*)(Vth + (size_t)(srow + 32) * NTOK + 0 + sseg * 8);

    for (int kv = 0; kv < NTOK; kv += 64) {
        __syncthreads();  // previous tile's compute done reading LDS
        *(uint4*)(&lK[srow * 64 + ssw0]) = rk0;
        *(uint4*)(&lK[(srow + 32) * 64 + ssw1]) = rk1;
        *(uint4*)(&lV[srow * 64 + ssw0]) = rv0;
        *(uint4*)(&lV[(srow + 32) * 64 + ssw1]) = rv1;
        __syncthreads();  // LDS tile ready

        int nkv = kv + 64;
        if (nkv < NTOK) {  // issue next tile's loads; land during compute
            rk0 = *(const uint4*)(K + (size_t)(nkv + srow) * EMB + head * HD + sseg * 8);
            rk1 = *(const uint4*)(K + (size_t)(nkv + srow + 32) * EMB + head * HD + sseg * 8);
            rv0 = *(const uint4*)(Vth + (size_t)srow * NTOK + nkv + sseg * 8);
            rv1 = *(const uint4*)(Vth + (size_t)(srow + 32) * NTOK + nkv + sseg * 8);
        }

        // scores: 16 q-rows x 64 k-cols per wave
        f32x4 s[4];
#pragma unroll
        for (int kj = 0; kj < 4; ++kj) {
            int r = kj * 16 + lr;
            const ushort* kb = &lK[r * 64];
            bf16x8 b0 = *(const bf16x8*)(kb + ((lg ^ (r & 7)) * 8));
            bf16x8 b1 = *(const bf16x8*)(kb + (((lg + 4) ^ (r & 7)) * 8));
            f32x4 acc = {};
            acc = MFMA16(q0, b0, acc);
            acc = MFMA16(q1, b1, acc);
            s[kj] = acc;
        }

        // online softmax in exp2 domain (rows j: lane covers row lg*4+j, col kj*16+lr)
        float pexp[4][4];
#pragma unroll
        for (int j = 0; j < 4; ++j) {
            float tm = fmaxf(fmaxf(s[0][j], s[1][j]), fmaxf(s[2][j], s[3][j]));
#pragma unroll
            for (int off = 1; off < 16; off <<= 1) tm = fmaxf(tm, __shfl_xor(tm, off));
            float mn = fmaxf(m[j], tm);
            float sc = exp2f(m[j] - mn);
            float rs = 0.0f;
#pragma unroll
            for (int kj = 0; kj < 4; ++kj) {
                float e = exp2f(s[kj][j] - mn);
                pexp[kj][j] = e;
                rs += e;
            }
#pragma unroll
            for (int off = 1; off < 16; off <<= 1) rs += __shfl_xor(rs, off);
            ls[j] = ls[j] * sc + rs;
            m[j] = mn;
#pragma unroll
            for (int dblk = 0; dblk < 4; ++dblk) oacc[dblk][j] *= sc;
        }

        // P -> per-wave LDS (bf16, swizzled), then re-fragment for PV
#pragma unroll
        for (int kj = 0; kj < 4; ++kj)
#pragma unroll
            for (int j = 0; j < 4; ++j) {
                int rowp = lg * 4 + j;
                lPw[rowp * 64 + ((kj * 16 + lr) ^ ((rowp & 7) << 3))] = f2bf(pexp[kj][j]);
            }

        bf16x8 pa0 = *(const bf16x8*)(&lPw[lr * 64 + ((lg ^ (lr & 7)) * 8)]);
        bf16x8 pa1 = *(const bf16x8*)(&lPw[lr * 64 + (((lg + 4) ^ (lr & 7)) * 8)]);
#pragma unroll
        for (int dblk = 0; dblk < 4; ++dblk) {
            int r = dblk * 16 + lr;
            const ushort* vb = &lV[r * 64];
            bf16x8 v0 = *(const bf16x8*)(vb + ((lg ^ (r & 7)) * 8));
            bf16x8 v1 = *(const bf16x8*)(vb + (((lg + 4) ^ (r & 7)) * 8));
            oacc[dblk] = MFMA16(pa0, v0, oacc[dblk]);
            oacc[dblk] = MFMA16(pa1, v1, oacc[dblk]);
        }
    }

    float inv[4];
#pragma unroll
    for (int j = 0; j < 4; ++j) inv[j] = 1.0f / ls[j];
#pragma unroll
    for (int dblk = 0; dblk < 4; ++dblk)
#pragma unroll
        for (int j = 0; j < 4; ++j) {
            int R = qbase + w * 16 + lg * 4 + j;
            int col = head * HD + dblk * 16 + lr;
            Ctx[(size_t)R * EMB + col] = f2bf(oacc[dblk][j] * inv[j]);
        }
}

// ---------------- output projection: out = Ctx @ Wo^T + bo + X ----------------
__global__ __launch_bounds__(256) void out_proj(const ushort* __restrict__ C0,
                                                const ushort* __restrict__ C1,
                                                const ushort* __restrict__ Wo,
                                                const float* __restrict__ bo,
                                                const float* __restrict__ A,
                                                const float* __restrict__ B,
                                                float* __restrict__ out) {
    int dir = blockIdx.z;
    const ushort* Ctx = dir ? C1 : C0;
    const float* X = dir ? B : A;
    float* o = out + (size_t)dir * NTOK * EMB;

    int w = threadIdx.x >> 6, lane = threadIdx.x & 63;
    int lr = lane & 15, lg = lane >> 4;
    int rbase = blockIdx.x * 64 + w * 16;
    int cbase = blockIdx.y * 64;

    f32x4 acc[4] = {};
#pragma unroll
    for (int kk = 0; kk < 256; kk += 32) {
        bf16x8 a = *(const bf16x8*)(Ctx + (size_t)(rbase + lr) * EMB + kk + lg * 8);
#pragma unroll
        for (int cj = 0; cj < 4; ++cj) {
            bf16x8 b = *(const bf16x8*)(Wo + (size_t)(cbase + cj * 16 + lr) * EMB + kk + lg * 8);
            acc[cj] = MFMA16(a, b, acc[cj]);
        }
    }
#pragma unroll
    for (int cj = 0; cj < 4; ++cj)
#pragma unroll
        for (int j = 0; j < 4; ++j) {
            int R = rbase + lg * 4 + j;
            int col = cbase + cj * 16 + lr;
            o[(size_t)R * EMB + col] = acc[cj][j] + bo[col] + X[(size_t)R * EMB + col];
        }
}

extern "C" void kernel_launch(void* const* d_in, const int* in_sizes, int n_in,
                              void* d_out, int out_size, void* d_ws, size_t ws_size,
                              hipStream_t stream) {
    const float* A  = (const float*)d_in[0];
    const float* B  = (const float*)d_in[1];
    const float* Wq = (const float*)d_in[2];
    const float* Wk = (const float*)d_in[3];
    const float* Wv = (const float*)d_in[4];
    const float* Wo = (const float*)d_in[5];
    const float* bo = (const float*)d_in[6];
    float* out = (float*)d_out;

    ushort* ws = (ushort*)d_ws;
    const size_t TE = (size_t)NTOK * EMB;  // 1048576 elements
    ushort* wall = ws;                 // 4 * 65536
    ushort* abf = wall + 4 * 65536;
    ushort* bbf = abf + TE;
    ushort* q0  = bbf + TE;
    ushort* q1  = q0 + TE;
    ushort* k0  = q1 + TE;
    ushort* k1  = k0 + TE;
    ushort* vt0 = k1 + TE;
    ushort* vt1 = vt0 + TE;
    ushort* c0  = vt1 + TE;
    ushort* c1  = c0 + TE;

    cvtAB<<<dim3(1024, 2), 256, 0, stream>>>(A, B, abf, bbf);
    cvtW<<<dim3(64, 4), 256, 0, stream>>>(Wq, Wk, Wv, Wo, wall);

    // z 0..2: A -> Q(dir0), K(dir1), V(dir1); z 3..5: B -> Q(dir1), K(dir0), V(dir0)
    qkv_proj<<<dim3(64, 4, 6), 256, 0, stream>>>(abf, bbf, wall, q0, k1, vt1, q1, k0, vt0);

    attn<<<dim3(64, HEADS, 2), 256, 0, stream>>>(q0, k0, vt0, c0, q1, k1, vt1, c1);

    out_proj<<<dim3(64, 4, 2), 256, 0, stream>>>(c0, c1, wall + 3 * 65536, bo, A, B, out);
}

// Round 3
// 135.487 us; speedup vs baseline: 2.1209x; 1.3811x over previous
//
#include <hip/hip_runtime.h>
#include <hip/hip_bf16.h>
#include <math.h>

#define EMB 256
#define HEADS 4
#define HD 64
#define NTOK 4096

typedef __attribute__((ext_vector_type(8))) short bf16x8;
typedef __attribute__((ext_vector_type(4))) float f32x4;
typedef __attribute__((ext_vector_type(16))) float f32x16;

#define MFMA16(a, b, c) __builtin_amdgcn_mfma_f32_16x16x32_bf16(a, b, c, 0, 0, 0)
#define MFMA32(a, b, c) __builtin_amdgcn_mfma_f32_32x32x16_bf16(a, b, c, 0, 0, 0)

static __device__ __forceinline__ ushort f2bf(float f) {
    __hip_bfloat16 h = __float2bfloat16(f);
    return *(ushort*)&h;
}

// ---------------- f32 -> bf16 conversion ----------------
__global__ void cvtAB(const float* __restrict__ A, const float* __restrict__ B,
                      ushort* __restrict__ Ao, ushort* __restrict__ Bo) {
    const float* s = blockIdx.y ? B : A;
    ushort* d = blockIdx.y ? Bo : Ao;
    int i = (blockIdx.x * 256 + threadIdx.x) * 4;
    float4 v = *(const float4*)(s + i);
    ushort4 o;
    o.x = f2bf(v.x); o.y = f2bf(v.y); o.z = f2bf(v.z); o.w = f2bf(v.w);
    *(ushort4*)(d + i) = o;
}

__global__ void cvtW(const float* __restrict__ Wq, const float* __restrict__ Wk,
                     const float* __restrict__ Wv, const float* __restrict__ Wo,
                     ushort* __restrict__ Wall) {
    const float* s = (blockIdx.y == 0) ? Wq : (blockIdx.y == 1) ? Wk : (blockIdx.y == 2) ? Wv : Wo;
    ushort* d = Wall + (size_t)blockIdx.y * 65536;
    int i = (blockIdx.x * 256 + threadIdx.x) * 4;
    float4 v = *(const float4*)(s + i);
    ushort4 o;
    o.x = f2bf(v.x); o.y = f2bf(v.y); o.z = f2bf(v.z); o.w = f2bf(v.w);
    *(ushort4*)(d + i) = o;
}

// ---------------- QKV projection: out = X @ W^T (bf16 MFMA) ----------------
// kind=0: Q [m][256], pre-scaled by log2(e)/8;  kind=1: K [m][256]
// kind=2: V transposed per head, token index bit-2/3-swapped: Vt[h][d][perm(m)]
__global__ __launch_bounds__(256) void qkv_proj(const ushort* __restrict__ Xa,
                                                const ushort* __restrict__ Xb,
                                                const ushort* __restrict__ Wall,
                                                ushort* __restrict__ Q0, ushort* __restrict__ K1, ushort* __restrict__ Vt1,
                                                ushort* __restrict__ Q1, ushort* __restrict__ K0, ushort* __restrict__ Vt0) {
    int w = threadIdx.x >> 6, lane = threadIdx.x & 63;
    int lr = lane & 15, lg = lane >> 4;
    int z = blockIdx.z;
    int kind = (z < 3) ? z : z - 3;
    const ushort* X = (z < 3) ? Xa : Xb;
    ushort* Qo = (z < 3) ? Q0 : Q1;
    ushort* Ko = (z < 3) ? K1 : K0;
    ushort* Vto = (z < 3) ? Vt1 : Vt0;
    const ushort* W = Wall + (size_t)kind * 65536;
    int rbase = blockIdx.x * 64 + w * 16;
    int cbase = blockIdx.y * 64;

    f32x4 acc[4] = {};
#pragma unroll
    for (int kk = 0; kk < 256; kk += 32) {
        bf16x8 a = *(const bf16x8*)(X + (size_t)(rbase + lr) * EMB + kk + lg * 8);
#pragma unroll
        for (int cj = 0; cj < 4; ++cj) {
            bf16x8 b = *(const bf16x8*)(W + (size_t)(cbase + cj * 16 + lr) * EMB + kk + lg * 8);
            acc[cj] = MFMA16(a, b, acc[cj]);
        }
    }
    const float QS = 0.125f * 1.4426950408889634f;  // 1/sqrt(64) * log2(e)
#pragma unroll
    for (int cj = 0; cj < 4; ++cj)
#pragma unroll
        for (int j = 0; j < 4; ++j) {
            int R = rbase + lg * 4 + j;
            int col = cbase + cj * 16 + lr;
            float v = acc[cj][j];
            if (kind == 0) {
                Qo[(size_t)R * EMB + col] = f2bf(v * QS);
            } else if (kind == 1) {
                Ko[(size_t)R * EMB + col] = f2bf(v);
            } else {
                int h = col >> 6, d = col & 63;
                int Rp = (R & ~12) | ((R & 4) << 1) | ((R & 8) >> 1);  // swap bits 2,3
                Vto[(size_t)h * HD * NTOK + (size_t)d * NTOK + Rp] = f2bf(v);
            }
        }
}

// ---------------- flash cross-attention, swapped-QK 32x32, kv-split=2 ----------------
// grid (32,4,4): x=q-tile(128 rows), y=head, z=dir*2+split. 4 waves x 32 q-rows.
// Lane holds a full P row half for its own q=lane&31: softmax in-lane + 1 shfl(32).
// V pre-permuted (bits 2,3 of token) makes PV's P-fragment lane-local: no P LDS trip.
__global__ __launch_bounds__(256) void attn(const ushort* __restrict__ Q0,
                                            const ushort* __restrict__ K0,
                                            const ushort* __restrict__ Vt0,
                                            const ushort* __restrict__ Q1,
                                            const ushort* __restrict__ K1,
                                            const ushort* __restrict__ Vt1,
                                            float* __restrict__ Opart,
                                            float* __restrict__ ML) {
    __shared__ ushort lK[64 * 64];
    __shared__ ushort lV[64 * 64];

    // bijective XCD swizzle: 512 blocks, blocks sharing (head,z) land on one XCD
    int fb = blockIdx.x + 32 * blockIdx.y + 128 * blockIdx.z;
    int nf = (fb & 7) * 64 + (fb >> 3);
    int qt = nf & 31;
    int head = (nf >> 5) & 3;
    int z = nf >> 7;
    int dir = z >> 1, split = z & 1;

    const ushort* Q = dir ? Q1 : Q0;
    const ushort* K = dir ? K1 : K0;
    const ushort* Vt = dir ? Vt1 : Vt0;
    const ushort* Vth = Vt + (size_t)head * HD * NTOK;

    int wq = threadIdx.x >> 6;
    int lane = threadIdx.x & 63;
    int l31 = lane & 31, hi = lane >> 5;
    int kv0 = split * 2048;

    int qg = qt * 128 + wq * 32 + l31;
    bf16x8 qf[4];
#pragma unroll
    for (int ks = 0; ks < 4; ++ks)
        qf[ks] = *(const bf16x8*)(Q + (size_t)qg * EMB + head * 64 + ks * 16 + hi * 8);

    // staging: thread covers 16B chunks (srow,sseg) and (srow+32,sseg)
    int srow = threadIdx.x >> 3, sseg = threadIdx.x & 7;
    int ssw0 = (sseg ^ (srow & 7)) * 8;
    int ssw1 = (sseg ^ ((srow + 32) & 7)) * 8;

    uint4 rk0 = *(const uint4*)(K + (size_t)(kv0 + srow) * EMB + head * 64 + sseg * 8);
    uint4 rk1 = *(const uint4*)(K + (size_t)(kv0 + srow + 32) * EMB + head * 64 + sseg * 8);
    uint4 rv0 = *(const uint4*)(Vth + (size_t)srow * NTOK + kv0 + sseg * 8);
    uint4 rv1 = *(const uint4*)(Vth + (size_t)(srow + 32) * NTOK + kv0 + sseg * 8);

    float m = -1e30f, ls = 0.0f;
    f32x16 oacc0 = {};
    f32x16 oacc1 = {};
    int sw = l31 & 7;

    for (int t = 0; t < 32; ++t) {
        __syncthreads();
        *(uint4*)(&lK[srow * 64 + ssw0]) = rk0;
        *(uint4*)(&lK[(srow + 32) * 64 + ssw1]) = rk1;
        *(uint4*)(&lV[srow * 64 + ssw0]) = rv0;
        *(uint4*)(&lV[(srow + 32) * 64 + ssw1]) = rv1;
        __syncthreads();

        if (t < 31) {
            int nkv = kv0 + (t + 1) * 64;
            rk0 = *(const uint4*)(K + (size_t)(nkv + srow) * EMB + head * 64 + sseg * 8);
            rk1 = *(const uint4*)(K + (size_t)(nkv + srow + 32) * EMB + head * 64 + sseg * 8);
            rv0 = *(const uint4*)(Vth + (size_t)srow * NTOK + nkv + sseg * 8);
            rv1 = *(const uint4*)(Vth + (size_t)(srow + 32) * NTOK + nkv + sseg * 8);
        }

        // QK^T swapped: S^T tiles, lane holds 32 scores for q-row l31
        f32x16 sA = {}, sB = {};
#pragma unroll
        for (int ks = 0; ks < 4; ++ks) {
            bf16x8 ka = *(const bf16x8*)(&lK[l31 * 64 + ((ks * 2 + hi) ^ sw) * 8]);
            bf16x8 kb = *(const bf16x8*)(&lK[(32 + l31) * 64 + ((ks * 2 + hi) ^ sw) * 8]);
            sA = MFMA32(ka, qf[ks], sA);
            sB = MFMA32(kb, qf[ks], sB);
        }

        // online softmax (exp2 domain), in-lane + one cross at lane^32
        float tmax = sA[0];
#pragma unroll
        for (int r = 1; r < 16; ++r) tmax = fmaxf(tmax, sA[r]);
#pragma unroll
        for (int r = 0; r < 16; ++r) tmax = fmaxf(tmax, sB[r]);
        tmax = fmaxf(tmax, __shfl_xor(tmax, 32));
        float mn = fmaxf(m, tmax);
        float sc = exp2f(m - mn);
        m = mn;
        float rs = 0.0f;
#pragma unroll
        for (int r = 0; r < 16; ++r) { sA[r] = exp2f(sA[r] - mn); rs += sA[r]; }
#pragma unroll
        for (int r = 0; r < 16; ++r) { sB[r] = exp2f(sB[r] - mn); rs += sB[r]; }
        rs += __shfl_xor(rs, 32);
        ls = ls * sc + rs;
#pragma unroll
        for (int r = 0; r < 16; ++r) { oacc0[r] *= sc; oacc1[r] *= sc; }

        // lane-local P fragments (V was pre-permuted to match this order)
        bf16x8 pa[4];
#pragma unroll
        for (int ks = 0; ks < 4; ++ks) {
#pragma unroll
            for (int u = 0; u < 8; ++u) {
                float v = (ks < 2) ? sA[(ks & 1) * 8 + u] : sB[(ks & 1) * 8 + u];
                pa[ks][u] = (short)f2bf(v);
            }
        }

        // PV swapped: O[q=l31][d], d-tiles via A=Vt rows
#pragma unroll
        for (int ks = 0; ks < 4; ++ks) {
            bf16x8 va = *(const bf16x8*)(&lV[l31 * 64 + ((ks * 2 + hi) ^ sw) * 8]);
            bf16x8 vb = *(const bf16x8*)(&lV[(32 + l31) * 64 + ((ks * 2 + hi) ^ sw) * 8]);
            oacc0 = MFMA32(va, pa[ks], oacc0);
            oacc1 = MFMA32(vb, pa[ks], oacc1);
        }
    }

    // epilogue: unnormalized partials + (m, l)
    float* Ob = Opart + ((size_t)z * 4096 + qg) * 256 + head * 64;
#pragma unroll
    for (int r = 0; r < 16; ++r) {
        int crow = (r & 3) + 8 * (r >> 2) + 4 * hi;
        Ob[crow] = oacc0[r];
        Ob[32 + crow] = oacc1[r];
    }
    if (hi == 0) {
        float2* mlp = (float2*)ML;
        mlp[((size_t)z * 4 + head) * 4096 + qg] = make_float2(m, ls);
    }
}

// ---------------- merge the two kv-splits, normalize, write bf16 ctx ----------------
__global__ __launch_bounds__(256) void merge(const float* __restrict__ Opart,
                                             const float* __restrict__ ML,
                                             ushort* __restrict__ C0,
                                             ushort* __restrict__ C1) {
    int idx = blockIdx.x * 256 + threadIdx.x;  // 0..32767: (dir, q, head)
    int dir = idx >> 14;
    int rem = idx & 16383;
    int q = rem >> 2;
    int head = rem & 3;
    int z0 = dir * 2, z1 = z0 + 1;
    const float2* mlp = (const float2*)ML;
    float2 ml0 = mlp[((size_t)z0 * 4 + head) * 4096 + q];
    float2 ml1 = mlp[((size_t)z1 * 4 + head) * 4096 + q];
    float M = fmaxf(ml0.x, ml1.x);
    float w0 = exp2f(ml0.x - M), w1 = exp2f(ml1.x - M);
    float inv = 1.0f / (w0 * ml0.y + w1 * ml1.y);
    w0 *= inv; w1 *= inv;
    const float* O0 = Opart + ((size_t)z0 * 4096 + q) * 256 + head * 64;
    const float* O1 = Opart + ((size_t)z1 * 4096 + q) * 256 + head * 64;
    ushort* C = (dir ? C1 : C0) + (size_t)q * 256 + head * 64;
#pragma unroll
    for (int d = 0; d < 64; d += 4) {
        float4 a = *(const float4*)(O0 + d);
        float4 b = *(const float4*)(O1 + d);
        ushort4 o;
        o.x = f2bf(w0 * a.x + w1 * b.x);
        o.y = f2bf(w0 * a.y + w1 * b.y);
        o.z = f2bf(w0 * a.z + w1 * b.z);
        o.w = f2bf(w0 * a.w + w1 * b.w);
        *(ushort4*)(C + d) = o;
    }
}

// ---------------- output projection: out = Ctx @ Wo^T + bo + X ----------------
__global__ __launch_bounds__(256) void out_proj(const ushort* __restrict__ C0,
                                                const ushort* __restrict__ C1,
                                                const ushort* __restrict__ Wo,
                                                const float* __restrict__ bo,
                                                const float* __restrict__ A,
                                                const float* __restrict__ B,
                                                float* __restrict__ out) {
    int dir = blockIdx.z;
    const ushort* Ctx = dir ? C1 : C0;
    const float* X = dir ? B : A;
    float* o = out + (size_t)dir * NTOK * EMB;

    int w = threadIdx.x >> 6, lane = threadIdx.x & 63;
    int lr = lane & 15, lg = lane >> 4;
    int rbase = blockIdx.x * 64 + w * 16;
    int cbase = blockIdx.y * 64;

    f32x4 acc[4] = {};
#pragma unroll
    for (int kk = 0; kk < 256; kk += 32) {
        bf16x8 a = *(const bf16x8*)(Ctx + (size_t)(rbase + lr) * EMB + kk + lg * 8);
#pragma unroll
        for (int cj = 0; cj < 4; ++cj) {
            bf16x8 b = *(const bf16x8*)(Wo + (size_t)(cbase + cj * 16 + lr) * EMB + kk + lg * 8);
            acc[cj] = MFMA16(a, b, acc[cj]);
        }
    }
#pragma unroll
    for (int cj = 0; cj < 4; ++cj)
#pragma unroll
        for (int j = 0; j < 4; ++j) {
            int R = rbase + lg * 4 + j;
            int col = cbase + cj * 16 + lr;
            o[(size_t)R * EMB + col] = acc[cj][j] + bo[col] + X[(size_t)R * EMB + col];
        }
}

extern "C" void kernel_launch(void* const* d_in, const int* in_sizes, int n_in,
                              void* d_out, int out_size, void* d_ws, size_t ws_size,
                              hipStream_t stream) {
    const float* A  = (const float*)d_in[0];
    const float* B  = (const float*)d_in[1];
    const float* Wq = (const float*)d_in[2];
    const float* Wk = (const float*)d_in[3];
    const float* Wv = (const float*)d_in[4];
    const float* Wo = (const float*)d_in[5];
    const float* bo = (const float*)d_in[6];
    float* out = (float*)d_out;

    ushort* ws = (ushort*)d_ws;
    const size_t TE = (size_t)NTOK * EMB;  // 1048576 elements
    ushort* wall = ws;                 // 4 * 65536
    ushort* abf = wall + 4 * 65536;
    ushort* bbf = abf + TE;
    ushort* q0  = bbf + TE;
    ushort* q1  = q0 + TE;
    ushort* k0  = q1 + TE;
    ushort* k1  = k0 + TE;
    ushort* vt0 = k1 + TE;
    ushort* vt1 = vt0 + TE;
    ushort* c0  = vt1 + TE;
    ushort* c1  = c0 + TE;
    float* Opart = (float*)(c1 + TE);          // 4 x 4096 x 256 f32 = 16 MB
    float* ML    = Opart + (size_t)4 * 4096 * 256;  // 4 x 4 x 4096 float2

    cvtAB<<<dim3(1024, 2), 256, 0, stream>>>(A, B, abf, bbf);
    cvtW<<<dim3(64, 4), 256, 0, stream>>>(Wq, Wk, Wv, Wo, wall);

    // z 0..2: A -> Q(dir0), K(dir1), V(dir1); z 3..5: B -> Q(dir1), K(dir0), V(dir0)
    qkv_proj<<<dim3(64, 4, 6), 256, 0, stream>>>(abf, bbf, wall, q0, k1, vt1, q1, k0, vt0);

    attn<<<dim3(32, 4, 4), 256, 0, stream>>>(q0, k0, vt0, q1, k1, vt1, Opart, ML);

    merge<<<dim3(128), 256, 0, stream>>>(Opart, ML, c0, c1);

    out_proj<<<dim3(64, 4, 2), 256, 0, stream>>>(c0, c1, wall + 3 * 65536, bo, A, B, out);
}

// Round 4
// 134.704 us; speedup vs baseline: 2.1332x; 1.0058x over previous
//
#include <hip/hip_runtime.h>
#include <hip/hip_bf16.h>
#include <math.h>

#define EMB 256
#define HEADS 4
#define HD 64
#define NTOK 4096

typedef __attribute__((ext_vector_type(8))) short bf16x8;
typedef __attribute__((ext_vector_type(4))) float f32x4;
typedef __attribute__((ext_vector_type(16))) float f32x16;

#define MFMA16(a, b, c) __builtin_amdgcn_mfma_f32_16x16x32_bf16(a, b, c, 0, 0, 0)
#define MFMA32(a, b, c) __builtin_amdgcn_mfma_f32_32x32x16_bf16(a, b, c, 0, 0, 0)

static __device__ __forceinline__ ushort f2bf(float f) {
    __hip_bfloat16 h = __float2bfloat16(f);
    return *(ushort*)&h;
}
static __device__ __forceinline__ uint pkbf(float lo, float hi) {
    uint r;
    asm("v_cvt_pk_bf16_f32 %0, %1, %2" : "=v"(r) : "v"(lo), "v"(hi));
    return r;
}
static __device__ __forceinline__ float max3f(float a, float b, float c) {
    float r;
    asm("v_max3_f32 %0, %1, %2, %3" : "=v"(r) : "v"(a), "v"(b), "v"(c));
    return r;
}
// 8 f32 -> bf16x8 via 4 cvt_pk
static __device__ __forceinline__ bf16x8 cvt8(float4 a, float4 b) {
    union { uint u[4]; bf16x8 h; } pk;
    pk.u[0] = pkbf(a.x, a.y);
    pk.u[1] = pkbf(a.z, a.w);
    pk.u[2] = pkbf(b.x, b.y);
    pk.u[3] = pkbf(b.z, b.w);
    return pk.h;
}

// ---------------- weights f32 -> bf16 ----------------
__global__ void cvtW(const float* __restrict__ Wq, const float* __restrict__ Wk,
                     const float* __restrict__ Wv, const float* __restrict__ Wo,
                     ushort* __restrict__ Wall) {
    const float* s = (blockIdx.y == 0) ? Wq : (blockIdx.y == 1) ? Wk : (blockIdx.y == 2) ? Wv : Wo;
    ushort* d = Wall + (size_t)blockIdx.y * 65536;
    int i = (blockIdx.x * 256 + threadIdx.x) * 4;
    float4 v = *(const float4*)(s + i);
    ushort4 o;
    o.x = f2bf(v.x); o.y = f2bf(v.y); o.z = f2bf(v.z); o.w = f2bf(v.w);
    *(ushort4*)(d + i) = o;
}

// ---------------- QKV projection: out = X @ W^T, X read as f32, cvt in-reg ----------------
// kind=0: Q [m][256] pre-scaled by log2(e)/8; kind=1: K [m][256]
// kind=2: V transposed per head, token bit-2/3-swapped: Vt[h][d][perm(m)]
__global__ __launch_bounds__(256) void qkv_proj(const float* __restrict__ Xa,
                                                const float* __restrict__ Xb,
                                                const ushort* __restrict__ Wall,
                                                ushort* __restrict__ Q0, ushort* __restrict__ K1, ushort* __restrict__ Vt1,
                                                ushort* __restrict__ Q1, ushort* __restrict__ K0, ushort* __restrict__ Vt0) {
    int w = threadIdx.x >> 6, lane = threadIdx.x & 63;
    int lr = lane & 15, lg = lane >> 4;
    int z = blockIdx.z;
    int kind = (z < 3) ? z : z - 3;
    const float* X = (z < 3) ? Xa : Xb;
    ushort* Qo = (z < 3) ? Q0 : Q1;
    ushort* Ko = (z < 3) ? K1 : K0;
    ushort* Vto = (z < 3) ? Vt1 : Vt0;
    const ushort* W = Wall + (size_t)kind * 65536;
    int rbase = blockIdx.x * 64 + w * 16;
    int cbase = blockIdx.y * 64;

    f32x4 acc[4] = {};
#pragma unroll
    for (int kk = 0; kk < 256; kk += 32) {
        const float* xr = X + (size_t)(rbase + lr) * EMB + kk + lg * 8;
        bf16x8 a = cvt8(*(const float4*)xr, *(const float4*)(xr + 4));
#pragma unroll
        for (int cj = 0; cj < 4; ++cj) {
            bf16x8 b = *(const bf16x8*)(W + (size_t)(cbase + cj * 16 + lr) * EMB + kk + lg * 8);
            acc[cj] = MFMA16(a, b, acc[cj]);
        }
    }
    const float QS = 0.125f * 1.4426950408889634f;  // 1/sqrt(64) * log2(e)
#pragma unroll
    for (int cj = 0; cj < 4; ++cj)
#pragma unroll
        for (int j = 0; j < 4; ++j) {
            int R = rbase + lg * 4 + j;
            int col = cbase + cj * 16 + lr;
            float v = acc[cj][j];
            if (kind == 0) {
                Qo[(size_t)R * EMB + col] = f2bf(v * QS);
            } else if (kind == 1) {
                Ko[(size_t)R * EMB + col] = f2bf(v);
            } else {
                int h = col >> 6, d = col & 63;
                int Rp = (R & ~12) | ((R & 4) << 1) | ((R & 8) >> 1);  // swap bits 2,3
                Vto[(size_t)h * HD * NTOK + (size_t)d * NTOK + Rp] = f2bf(v);
            }
        }
}

// ---------------- flash cross-attention, swapped-QK 32x32, kv-split=2 ----------------
__global__ __launch_bounds__(256) void attn(const ushort* __restrict__ Q0,
                                            const ushort* __restrict__ K0,
                                            const ushort* __restrict__ Vt0,
                                            const ushort* __restrict__ Q1,
                                            const ushort* __restrict__ K1,
                                            const ushort* __restrict__ Vt1,
                                            float* __restrict__ Opart,
                                            float* __restrict__ ML) {
    __shared__ ushort lK[64 * 64];
    __shared__ ushort lV[64 * 64];

    // bijective XCD swizzle
    int fb = blockIdx.x + 32 * blockIdx.y + 128 * blockIdx.z;
    int nf = (fb & 7) * 64 + (fb >> 3);
    int qt = nf & 31;
    int head = (nf >> 5) & 3;
    int z = nf >> 7;
    int dir = z >> 1, split = z & 1;

    const ushort* Q = dir ? Q1 : Q0;
    const ushort* K = dir ? K1 : K0;
    const ushort* Vt = dir ? Vt1 : Vt0;
    const ushort* Vth = Vt + (size_t)head * HD * NTOK;

    int wq = threadIdx.x >> 6;
    int lane = threadIdx.x & 63;
    int l31 = lane & 31, hi = lane >> 5;
    int kv0 = split * 2048;

    int qg = qt * 128 + wq * 32 + l31;
    bf16x8 qf[4];
#pragma unroll
    for (int ks = 0; ks < 4; ++ks)
        qf[ks] = *(const bf16x8*)(Q + (size_t)qg * EMB + head * 64 + ks * 16 + hi * 8);

    int srow = threadIdx.x >> 3, sseg = threadIdx.x & 7;
    int ssw0 = (sseg ^ (srow & 7)) * 8;
    int ssw1 = (sseg ^ ((srow + 32) & 7)) * 8;

    uint4 rk0 = *(const uint4*)(K + (size_t)(kv0 + srow) * EMB + head * 64 + sseg * 8);
    uint4 rk1 = *(const uint4*)(K + (size_t)(kv0 + srow + 32) * EMB + head * 64 + sseg * 8);
    uint4 rv0 = *(const uint4*)(Vth + (size_t)srow * NTOK + kv0 + sseg * 8);
    uint4 rv1 = *(const uint4*)(Vth + (size_t)(srow + 32) * NTOK + kv0 + sseg * 8);

    float m = -1e30f, ls = 0.0f;
    f32x16 oacc0 = {};
    f32x16 oacc1 = {};
    int sw = l31 & 7;

    for (int t = 0; t < 32; ++t) {
        __syncthreads();
        *(uint4*)(&lK[srow * 64 + ssw0]) = rk0;
        *(uint4*)(&lK[(srow + 32) * 64 + ssw1]) = rk1;
        *(uint4*)(&lV[srow * 64 + ssw0]) = rv0;
        *(uint4*)(&lV[(srow + 32) * 64 + ssw1]) = rv1;
        __syncthreads();

        if (t < 31) {
            int nkv = kv0 + (t + 1) * 64;
            rk0 = *(const uint4*)(K + (size_t)(nkv + srow) * EMB + head * 64 + sseg * 8);
            rk1 = *(const uint4*)(K + (size_t)(nkv + srow + 32) * EMB + head * 64 + sseg * 8);
            rv0 = *(const uint4*)(Vth + (size_t)srow * NTOK + nkv + sseg * 8);
            rv1 = *(const uint4*)(Vth + (size_t)(srow + 32) * NTOK + nkv + sseg * 8);
        }

        // QK^T swapped: lane holds 32 scores for q-row l31
        f32x16 sA = {}, sB = {};
        __builtin_amdgcn_s_setprio(1);
#pragma unroll
        for (int ks = 0; ks < 4; ++ks) {
            bf16x8 ka = *(const bf16x8*)(&lK[l31 * 64 + ((ks * 2 + hi) ^ sw) * 8]);
            bf16x8 kb = *(const bf16x8*)(&lK[(32 + l31) * 64 + ((ks * 2 + hi) ^ sw) * 8]);
            sA = MFMA32(ka, qf[ks], sA);
            sB = MFMA32(kb, qf[ks], sB);
        }
        __builtin_amdgcn_s_setprio(0);

        // tile max via v_max3 tree (17 insts, depth 4)
        float t0 = max3f(sA[0], sA[1], sA[2]);
        float t1 = max3f(sA[3], sA[4], sA[5]);
        float t2 = max3f(sA[6], sA[7], sA[8]);
        float t3 = max3f(sA[9], sA[10], sA[11]);
        float t4 = max3f(sA[12], sA[13], sA[14]);
        float t5 = max3f(sB[0], sB[1], sB[2]);
        float t6 = max3f(sB[3], sB[4], sB[5]);
        float t7 = max3f(sB[6], sB[7], sB[8]);
        float t8 = max3f(sB[9], sB[10], sB[11]);
        float t9 = max3f(sB[12], sB[13], sB[14]);
        float ta = fmaxf(sA[15], sB[15]);
        float u0 = max3f(t0, t1, t2);
        float u1 = max3f(t3, t4, t5);
        float u2 = max3f(t6, t7, t8);
        float u3 = fmaxf(t9, ta);
        float tmax = fmaxf(max3f(u0, u1, u2), u3);
        tmax = fmaxf(tmax, __shfl_xor(tmax, 32));

        // defer-max (THR=8): rescale only if some lane's max grew past m+8
        if (__any(tmax > m + 8.0f)) {
            float mn = fmaxf(m, tmax);
            float sc = exp2f(m - mn);
            m = mn;
            ls *= sc;
#pragma unroll
            for (int r = 0; r < 16; ++r) { oacc0[r] *= sc; oacc1[r] *= sc; }
        }

#pragma unroll
        for (int r = 0; r < 16; ++r) sA[r] = exp2f(sA[r] - m);
#pragma unroll
        for (int r = 0; r < 16; ++r) sB[r] = exp2f(sB[r] - m);

        // pairwise-tree row sum (depth 5)
        float s1[16];
#pragma unroll
        for (int i = 0; i < 8; ++i) s1[i] = sA[2 * i] + sA[2 * i + 1];
#pragma unroll
        for (int i = 0; i < 8; ++i) s1[8 + i] = sB[2 * i] + sB[2 * i + 1];
#pragma unroll
        for (int w2 = 8; w2 >= 1; w2 >>= 1)
#pragma unroll
            for (int i = 0; i < 8; ++i)
                if (i < w2) s1[i] = s1[2 * i] + s1[2 * i + 1];
        float rs = s1[0];
        rs += __shfl_xor(rs, 32);
        ls += rs;

        // P -> bf16 fragments via HW cvt_pk (lane-local; V pre-permuted to match)
        bf16x8 pa[4];
#pragma unroll
        for (int ks = 0; ks < 4; ++ks) {
            union { uint u[4]; bf16x8 h; } pk;
#pragma unroll
            for (int j = 0; j < 4; ++j) {
                float lo = (ks < 2) ? sA[(ks & 1) * 8 + 2 * j] : sB[(ks & 1) * 8 + 2 * j];
                float hv = (ks < 2) ? sA[(ks & 1) * 8 + 2 * j + 1] : sB[(ks & 1) * 8 + 2 * j + 1];
                pk.u[j] = pkbf(lo, hv);
            }
            pa[ks] = pk.h;
        }

        __builtin_amdgcn_s_setprio(1);
#pragma unroll
        for (int ks = 0; ks < 4; ++ks) {
            bf16x8 va = *(const bf16x8*)(&lV[l31 * 64 + ((ks * 2 + hi) ^ sw) * 8]);
            bf16x8 vb = *(const bf16x8*)(&lV[(32 + l31) * 64 + ((ks * 2 + hi) ^ sw) * 8]);
            oacc0 = MFMA32(va, pa[ks], oacc0);
            oacc1 = MFMA32(vb, pa[ks], oacc1);
        }
        __builtin_amdgcn_s_setprio(0);
    }

    // epilogue: unnormalized partials + (m, l)
    float* Ob = Opart + ((size_t)z * 4096 + qg) * 256 + head * 64;
#pragma unroll
    for (int r = 0; r < 16; ++r) {
        int crow = (r & 3) + 8 * (r >> 2) + 4 * hi;
        Ob[crow] = oacc0[r];
        Ob[32 + crow] = oacc1[r];
    }
    if (hi == 0) {
        float2* mlp = (float2*)ML;
        mlp[((size_t)z * 4 + head) * 4096 + qg] = make_float2(m, ls);
    }
}

// ---------------- fused merge + output projection: out = norm(Opart) @ Wo^T + bo + X ----------------
__global__ __launch_bounds__(256) void out_proj(const float* __restrict__ Opart,
                                                const float* __restrict__ ML,
                                                const ushort* __restrict__ Wo,
                                                const float* __restrict__ bo,
                                                const float* __restrict__ A,
                                                const float* __restrict__ B,
                                                float* __restrict__ out) {
    int dir = blockIdx.z;
    const float* X = dir ? B : A;
    float* o = out + (size_t)dir * NTOK * EMB;

    int w = threadIdx.x >> 6, lane = threadIdx.x & 63;
    int lr = lane & 15, lg = lane >> 4;
    int rbase = blockIdx.x * 64 + w * 16;
    int cbase = blockIdx.y * 64;
    int R = rbase + lr;  // A-fragment row for this lane

    // per-head normalized merge weights for row R
    const float2* mlp = (const float2*)ML;
    float W0[4], W1[4];
#pragma unroll
    for (int h = 0; h < 4; ++h) {
        float2 ml0 = mlp[((size_t)(dir * 2 + 0) * 4 + h) * 4096 + R];
        float2 ml1 = mlp[((size_t)(dir * 2 + 1) * 4 + h) * 4096 + R];
        float M = fmaxf(ml0.x, ml1.x);
        float a0 = exp2f(ml0.x - M), a1 = exp2f(ml1.x - M);
        float inv = 1.0f / (a0 * ml0.y + a1 * ml1.y);
        W0[h] = a0 * inv;
        W1[h] = a1 * inv;
    }

    const float* O0r = Opart + ((size_t)(dir * 2 + 0) * 4096 + R) * 256;
    const float* O1r = Opart + ((size_t)(dir * 2 + 1) * 4096 + R) * 256;

    f32x4 acc[4] = {};
#pragma unroll
    for (int kk = 0; kk < 256; kk += 32) {
        int h = kk >> 6;
        float w0 = W0[h], w1 = W1[h];
        float4 x0 = *(const float4*)(O0r + kk + lg * 8);
        float4 x1 = *(const float4*)(O0r + kk + lg * 8 + 4);
        float4 y0 = *(const float4*)(O1r + kk + lg * 8);
        float4 y1 = *(const float4*)(O1r + kk + lg * 8 + 4);
        float4 c0, c1;
        c0.x = w0 * x0.x + w1 * y0.x; c0.y = w0 * x0.y + w1 * y0.y;
        c0.z = w0 * x0.z + w1 * y0.z; c0.w = w0 * x0.w + w1 * y0.w;
        c1.x = w0 * x1.x + w1 * y1.x; c1.y = w0 * x1.y + w1 * y1.y;
        c1.z = w0 * x1.z + w1 * y1.z; c1.w = w0 * x1.w + w1 * y1.w;
        bf16x8 a = cvt8(c0, c1);
#pragma unroll
        for (int cj = 0; cj < 4; ++cj) {
            bf16x8 b = *(const bf16x8*)(Wo + (size_t)(cbase + cj * 16 + lr) * EMB + kk + lg * 8);
            acc[cj] = MFMA16(a, b, acc[cj]);
        }
    }
#pragma unroll
    for (int cj = 0; cj < 4; ++cj)
#pragma unroll
        for (int j = 0; j < 4; ++j) {
            int Rr = rbase + lg * 4 + j;
            int col = cbase + cj * 16 + lr;
            o[(size_t)Rr * EMB + col] = acc[cj][j] + bo[col] + X[(size_t)Rr * EMB + col];
        }
}

extern "C" void kernel_launch(void* const* d_in, const int* in_sizes, int n_in,
                              void* d_out, int out_size, void* d_ws, size_t ws_size,
                              hipStream_t stream) {
    const float* A  = (const float*)d_in[0];
    const float* B  = (const float*)d_in[1];
    const float* Wq = (const float*)d_in[2];
    const float* Wk = (const float*)d_in[3];
    const float* Wv = (const float*)d_in[4];
    const float* Wo = (const float*)d_in[5];
    const float* bo = (const float*)d_in[6];
    float* out = (float*)d_out;

    ushort* ws = (ushort*)d_ws;
    const size_t TE = (size_t)NTOK * EMB;  // 1048576 elements
    ushort* wall = ws;                 // 4 * 65536
    ushort* q0  = wall + 4 * 65536;
    ushort* q1  = q0 + TE;
    ushort* k0  = q1 + TE;
    ushort* k1  = k0 + TE;
    ushort* vt0 = k1 + TE;
    ushort* vt1 = vt0 + TE;
    float* Opart = (float*)(vt1 + TE);              // 4 x 4096 x 256 f32 = 16 MB
    float* ML    = Opart + (size_t)4 * 4096 * 256;  // 4 x 4 x 4096 float2

    cvtW<<<dim3(64, 4), 256, 0, stream>>>(Wq, Wk, Wv, Wo, wall);

    // z 0..2: A -> Q(dir0), K(dir1), V(dir1); z 3..5: B -> Q(dir1), K(dir0), V(dir0)
    qkv_proj<<<dim3(64, 4, 6), 256, 0, stream>>>(A, B, wall, q0, k1, vt1, q1, k0, vt0);

    attn<<<dim3(32, 4, 4), 256, 0, stream>>>(q0, k0, vt0, q1, k1, vt1, Opart, ML);

    out_proj<<<dim3(64, 4, 2), 256, 0, stream>>>(Opart, ML, wall + 3 * 65536, bo, A, B, out);
}

// Round 5
// 113.784 us; speedup vs baseline: 2.5254x; 1.1839x over previous
//
#include <hip/hip_runtime.h>
#include <hip/hip_bf16.h>
#include <math.h>

#define EMB 256
#define HEADS 4
#define HD 64
#define NTOK 4096

typedef __attribute__((ext_vector_type(8))) short bf16x8;
typedef __attribute__((ext_vector_type(4))) float f32x4;
typedef __attribute__((ext_vector_type(16))) float f32x16;

#define MFMA16(a, b, c) __builtin_amdgcn_mfma_f32_16x16x32_bf16(a, b, c, 0, 0, 0)
#define MFMA32(a, b, c) __builtin_amdgcn_mfma_f32_32x32x16_bf16(a, b, c, 0, 0, 0)

static __device__ __forceinline__ ushort f2bf(float f) {
    __hip_bfloat16 h = __float2bfloat16(f);
    return *(ushort*)&h;
}
static __device__ __forceinline__ float ex2(float x) { return __builtin_amdgcn_exp2f(x); }
static __device__ __forceinline__ uint pkbf(float lo, float hi) {
    uint r;
    asm("v_cvt_pk_bf16_f32 %0, %1, %2" : "=v"(r) : "v"(lo), "v"(hi));
    return r;
}
static __device__ __forceinline__ float max3f(float a, float b, float c) {
    float r;
    asm("v_max3_f32 %0, %1, %2, %3" : "=v"(r) : "v"(a), "v"(b), "v"(c));
    return r;
}
static __device__ __forceinline__ bf16x8 cvt8(float4 a, float4 b) {
    union { uint u[4]; bf16x8 h; } pk;
    pk.u[0] = pkbf(a.x, a.y);
    pk.u[1] = pkbf(a.z, a.w);
    pk.u[2] = pkbf(b.x, b.y);
    pk.u[3] = pkbf(b.z, b.w);
    return pk.h;
}
static __device__ __forceinline__ float bf2f(ushort u) {
    return __uint_as_float(((uint)u) << 16);
}

// ---------------- weights f32 -> bf16 ----------------
__global__ void cvtW(const float* __restrict__ Wq, const float* __restrict__ Wk,
                     const float* __restrict__ Wv, const float* __restrict__ Wo,
                     ushort* __restrict__ Wall) {
    const float* s = (blockIdx.y == 0) ? Wq : (blockIdx.y == 1) ? Wk : (blockIdx.y == 2) ? Wv : Wo;
    ushort* d = Wall + (size_t)blockIdx.y * 65536;
    int i = (blockIdx.x * 256 + threadIdx.x) * 4;
    float4 v = *(const float4*)(s + i);
    ushort4 o;
    o.x = f2bf(v.x); o.y = f2bf(v.y); o.z = f2bf(v.z); o.w = f2bf(v.w);
    *(ushort4*)(d + i) = o;
}

// ---------------- QKV projection: out = X @ W^T, X read as f32, cvt in-reg ----------------
// kind=0: Q [m][256] pre-scaled by log2(e)/8; kind=1: K [m][256]
// kind=2: V transposed per head, token bit-2/3-swapped: Vt[h][d][perm(m)]
__global__ __launch_bounds__(256) void qkv_proj(const float* __restrict__ Xa,
                                                const float* __restrict__ Xb,
                                                const ushort* __restrict__ Wall,
                                                ushort* __restrict__ Q0, ushort* __restrict__ K1, ushort* __restrict__ Vt1,
                                                ushort* __restrict__ Q1, ushort* __restrict__ K0, ushort* __restrict__ Vt0) {
    int w = threadIdx.x >> 6, lane = threadIdx.x & 63;
    int lr = lane & 15, lg = lane >> 4;
    int z = blockIdx.z;
    int kind = (z < 3) ? z : z - 3;
    const float* X = (z < 3) ? Xa : Xb;
    ushort* Qo = (z < 3) ? Q0 : Q1;
    ushort* Ko = (z < 3) ? K1 : K0;
    ushort* Vto = (z < 3) ? Vt1 : Vt0;
    const ushort* W = Wall + (size_t)kind * 65536;
    int rbase = blockIdx.x * 64 + w * 16;
    int cbase = blockIdx.y * 64;

    f32x4 acc[4] = {};
#pragma unroll
    for (int kk = 0; kk < 256; kk += 32) {
        const float* xr = X + (size_t)(rbase + lr) * EMB + kk + lg * 8;
        bf16x8 a = cvt8(*(const float4*)xr, *(const float4*)(xr + 4));
#pragma unroll
        for (int cj = 0; cj < 4; ++cj) {
            bf16x8 b = *(const bf16x8*)(W + (size_t)(cbase + cj * 16 + lr) * EMB + kk + lg * 8);
            acc[cj] = MFMA16(a, b, acc[cj]);
        }
    }
    const float QS = 0.125f * 1.4426950408889634f;  // 1/sqrt(64) * log2(e)
#pragma unroll
    for (int cj = 0; cj < 4; ++cj)
#pragma unroll
        for (int j = 0; j < 4; ++j) {
            int R = rbase + lg * 4 + j;
            int col = cbase + cj * 16 + lr;
            float v = acc[cj][j];
            if (kind == 0) {
                Qo[(size_t)R * EMB + col] = f2bf(v * QS);
            } else if (kind == 1) {
                Ko[(size_t)R * EMB + col] = f2bf(v);
            } else {
                int h = col >> 6, d = col & 63;
                int Rp = (R & ~12) | ((R & 4) << 1) | ((R & 8) >> 1);  // swap bits 2,3
                Vto[(size_t)h * HD * NTOK + (size_t)d * NTOK + Rp] = f2bf(v);
            }
        }
}

// ---------------- flash cross-attention, swapped-QK 32x32, kv-split=4 ----------------
// grid (32,4,8): 1024 blocks = 4 blocks/CU. Double-buffered LDS, ONE barrier/tile.
__global__ __launch_bounds__(256, 4) void attn(const ushort* __restrict__ Q0,
                                               const ushort* __restrict__ K0,
                                               const ushort* __restrict__ Vt0,
                                               const ushort* __restrict__ Q1,
                                               const ushort* __restrict__ K1,
                                               const ushort* __restrict__ Vt1,
                                               ushort* __restrict__ Opart,
                                               float* __restrict__ ML) {
    __shared__ ushort lK[2][64 * 64];
    __shared__ ushort lV[2][64 * 64];

    // bijective XCD swizzle over 1024 blocks
    int fb = blockIdx.x + 32 * blockIdx.y + 128 * blockIdx.z;
    int nf = (fb & 7) * 128 + (fb >> 3);
    int qt = nf & 31;
    int head = (nf >> 5) & 3;
    int z = nf >> 7;               // 0..7
    int dir = z >> 2, split = z & 3;
    int kv0 = split * 1024;

    const ushort* Q = dir ? Q1 : Q0;
    const ushort* K = dir ? K1 : K0;
    const ushort* Vt = dir ? Vt1 : Vt0;
    const ushort* Vth = Vt + (size_t)head * HD * NTOK;

    int wq = threadIdx.x >> 6;
    int lane = threadIdx.x & 63;
    int l31 = lane & 31, hi = lane >> 5;

    int qg = qt * 128 + wq * 32 + l31;
    bf16x8 qf[4];
#pragma unroll
    for (int ks = 0; ks < 4; ++ks)
        qf[ks] = *(const bf16x8*)(Q + (size_t)qg * EMB + head * 64 + ks * 16 + hi * 8);

    int srow = threadIdx.x >> 3, sseg = threadIdx.x & 7;
    int ssw0 = (sseg ^ (srow & 7)) * 8;
    int ssw1 = (sseg ^ ((srow + 32) & 7)) * 8;

    // prologue: prefetch tile 0
    uint4 rk0 = *(const uint4*)(K + (size_t)(kv0 + srow) * EMB + head * 64 + sseg * 8);
    uint4 rk1 = *(const uint4*)(K + (size_t)(kv0 + srow + 32) * EMB + head * 64 + sseg * 8);
    uint4 rv0 = *(const uint4*)(Vth + (size_t)srow * NTOK + kv0 + sseg * 8);
    uint4 rv1 = *(const uint4*)(Vth + (size_t)(srow + 32) * NTOK + kv0 + sseg * 8);

    float m = -1e30f, ls = 0.0f;
    f32x16 oacc0 = {};
    f32x16 oacc1 = {};
    int sw = l31 & 7;

    for (int t = 0; t < 16; ++t) {
        int cur = t & 1;
        ushort* lk = &lK[cur][0];
        ushort* lv = &lV[cur][0];
        // write prefetched tile into current buffer (other waves still compute on buf^1)
        *(uint4*)(&lk[srow * 64 + ssw0]) = rk0;
        *(uint4*)(&lk[(srow + 32) * 64 + ssw1]) = rk1;
        *(uint4*)(&lv[srow * 64 + ssw0]) = rv0;
        *(uint4*)(&lv[(srow + 32) * 64 + ssw1]) = rv1;
        __syncthreads();  // sole barrier: buffer ready for all

        if (t < 15) {
            int nkv = kv0 + (t + 1) * 64;
            rk0 = *(const uint4*)(K + (size_t)(nkv + srow) * EMB + head * 64 + sseg * 8);
            rk1 = *(const uint4*)(K + (size_t)(nkv + srow + 32) * EMB + head * 64 + sseg * 8);
            rv0 = *(const uint4*)(Vth + (size_t)srow * NTOK + nkv + sseg * 8);
            rv1 = *(const uint4*)(Vth + (size_t)(srow + 32) * NTOK + nkv + sseg * 8);
        }

        // QK^T swapped: lane holds 32 scores for q-row l31
        f32x16 sA = {}, sB = {};
        __builtin_amdgcn_s_setprio(1);
#pragma unroll
        for (int ks = 0; ks < 4; ++ks) {
            bf16x8 ka = *(const bf16x8*)(&lk[l31 * 64 + ((ks * 2 + hi) ^ sw) * 8]);
            bf16x8 kb = *(const bf16x8*)(&lk[(32 + l31) * 64 + ((ks * 2 + hi) ^ sw) * 8]);
            sA = MFMA32(ka, qf[ks], sA);
            sB = MFMA32(kb, qf[ks], sB);
        }
        __builtin_amdgcn_s_setprio(0);

        // tile max via v_max3 tree
        float t0 = max3f(sA[0], sA[1], sA[2]);
        float t1 = max3f(sA[3], sA[4], sA[5]);
        float t2 = max3f(sA[6], sA[7], sA[8]);
        float t3 = max3f(sA[9], sA[10], sA[11]);
        float t4 = max3f(sA[12], sA[13], sA[14]);
        float t5 = max3f(sB[0], sB[1], sB[2]);
        float t6 = max3f(sB[3], sB[4], sB[5]);
        float t7 = max3f(sB[6], sB[7], sB[8]);
        float t8 = max3f(sB[9], sB[10], sB[11]);
        float t9 = max3f(sB[12], sB[13], sB[14]);
        float ta = fmaxf(sA[15], sB[15]);
        float u0 = max3f(t0, t1, t2);
        float u1 = max3f(t3, t4, t5);
        float u2 = max3f(t6, t7, t8);
        float u3 = fmaxf(t9, ta);
        float tmax = fmaxf(max3f(u0, u1, u2), u3);
        tmax = fmaxf(tmax, __shfl_xor(tmax, 32));

        // defer-max (THR=8)
        if (__any(tmax > m + 8.0f)) {
            float mn = fmaxf(m, tmax);
            float sc = ex2(m - mn);
            m = mn;
            ls *= sc;
#pragma unroll
            for (int r = 0; r < 16; ++r) { oacc0[r] *= sc; oacc1[r] *= sc; }
        }

#pragma unroll
        for (int r = 0; r < 16; ++r) sA[r] = ex2(sA[r] - m);
#pragma unroll
        for (int r = 0; r < 16; ++r) sB[r] = ex2(sB[r] - m);

        // pairwise-tree row sum
        float s1[16];
#pragma unroll
        for (int i = 0; i < 8; ++i) s1[i] = sA[2 * i] + sA[2 * i + 1];
#pragma unroll
        for (int i = 0; i < 8; ++i) s1[8 + i] = sB[2 * i] + sB[2 * i + 1];
#pragma unroll
        for (int w2 = 8; w2 >= 1; w2 >>= 1)
#pragma unroll
            for (int i = 0; i < 8; ++i)
                if (i < w2) s1[i] = s1[2 * i] + s1[2 * i + 1];
        float rs = s1[0];
        rs += __shfl_xor(rs, 32);
        ls += rs;

        // P -> bf16 fragments (lane-local; V pre-permuted to match)
        bf16x8 pa[4];
#pragma unroll
        for (int ks = 0; ks < 4; ++ks) {
            union { uint u[4]; bf16x8 h; } pk;
#pragma unroll
            for (int j = 0; j < 4; ++j) {
                float lo = (ks < 2) ? sA[(ks & 1) * 8 + 2 * j] : sB[(ks & 1) * 8 + 2 * j];
                float hv = (ks < 2) ? sA[(ks & 1) * 8 + 2 * j + 1] : sB[(ks & 1) * 8 + 2 * j + 1];
                pk.u[j] = pkbf(lo, hv);
            }
            pa[ks] = pk.h;
        }

        __builtin_amdgcn_s_setprio(1);
#pragma unroll
        for (int ks = 0; ks < 4; ++ks) {
            bf16x8 va = *(const bf16x8*)(&lv[l31 * 64 + ((ks * 2 + hi) ^ sw) * 8]);
            bf16x8 vb = *(const bf16x8*)(&lv[(32 + l31) * 64 + ((ks * 2 + hi) ^ sw) * 8]);
            oacc0 = MFMA32(va, pa[ks], oacc0);
            oacc1 = MFMA32(vb, pa[ks], oacc1);
        }
        __builtin_amdgcn_s_setprio(0);
    }

    // epilogue: unnormalized bf16 partials + (m, l)
    ushort* Ob = Opart + ((size_t)z * 4096 + qg) * 256 + head * 64;
#pragma unroll
    for (int r = 0; r < 16; ++r) {
        int crow = (r & 3) + 8 * (r >> 2) + 4 * hi;
        Ob[crow] = f2bf(oacc0[r]);
        Ob[32 + crow] = f2bf(oacc1[r]);
    }
    if (hi == 0) {
        float2* mlp = (float2*)ML;
        mlp[((size_t)z * 4 + head) * 4096 + qg] = make_float2(m, ls);
    }
}

// ---------------- fused 4-way merge + output projection ----------------
__global__ __launch_bounds__(256) void out_proj(const ushort* __restrict__ Opart,
                                                const float* __restrict__ ML,
                                                const ushort* __restrict__ Wo,
                                                const float* __restrict__ bo,
                                                const float* __restrict__ A,
                                                const float* __restrict__ B,
                                                float* __restrict__ out) {
    int dir = blockIdx.z;
    const float* X = dir ? B : A;
    float* o = out + (size_t)dir * NTOK * EMB;

    int w = threadIdx.x >> 6, lane = threadIdx.x & 63;
    int lr = lane & 15, lg = lane >> 4;
    int rbase = blockIdx.x * 64 + w * 16;
    int cbase = blockIdx.y * 64;
    int R = rbase + lr;  // A-fragment row for this lane

    // per-head normalized merge weights over the 4 kv-splits
    const float2* mlp = (const float2*)ML;
    float Wm[4][4];
#pragma unroll
    for (int h = 0; h < 4; ++h) {
        float2 ml[4];
        float M = -1e30f;
#pragma unroll
        for (int s = 0; s < 4; ++s) {
            ml[s] = mlp[((size_t)(dir * 4 + s) * 4 + h) * 4096 + R];
            M = fmaxf(M, ml[s].x);
        }
        float denom = 0.0f, a[4];
#pragma unroll
        for (int s = 0; s < 4; ++s) { a[s] = ex2(ml[s].x - M); denom += a[s] * ml[s].y; }
        float inv = 1.0f / denom;
#pragma unroll
        for (int s = 0; s < 4; ++s) Wm[h][s] = a[s] * inv;
    }

    const ushort* Or[4];
#pragma unroll
    for (int s = 0; s < 4; ++s)
        Or[s] = Opart + ((size_t)(dir * 4 + s) * 4096 + R) * 256;

    f32x4 acc[4] = {};
#pragma unroll
    for (int kk = 0; kk < 256; kk += 32) {
        int h = kk >> 6;
        bf16x8 xs0 = *(const bf16x8*)(Or[0] + kk + lg * 8);
        bf16x8 xs1 = *(const bf16x8*)(Or[1] + kk + lg * 8);
        bf16x8 xs2 = *(const bf16x8*)(Or[2] + kk + lg * 8);
        bf16x8 xs3 = *(const bf16x8*)(Or[3] + kk + lg * 8);
        float cv[8];
#pragma unroll
        for (int u = 0; u < 8; ++u) {
            cv[u] = Wm[h][0] * bf2f((ushort)xs0[u]) + Wm[h][1] * bf2f((ushort)xs1[u])
                  + Wm[h][2] * bf2f((ushort)xs2[u]) + Wm[h][3] * bf2f((ushort)xs3[u]);
        }
        float4 c0 = {cv[0], cv[1], cv[2], cv[3]};
        float4 c1 = {cv[4], cv[5], cv[6], cv[7]};
        bf16x8 a = cvt8(c0, c1);
#pragma unroll
        for (int cj = 0; cj < 4; ++cj) {
            bf16x8 b = *(const bf16x8*)(Wo + (size_t)(cbase + cj * 16 + lr) * EMB + kk + lg * 8);
            acc[cj] = MFMA16(a, b, acc[cj]);
        }
    }
#pragma unroll
    for (int cj = 0; cj < 4; ++cj)
#pragma unroll
        for (int j = 0; j < 4; ++j) {
            int Rr = rbase + lg * 4 + j;
            int col = cbase + cj * 16 + lr;
            o[(size_t)Rr * EMB + col] = acc[cj][j] + bo[col] + X[(size_t)Rr * EMB + col];
        }
}

extern "C" void kernel_launch(void* const* d_in, const int* in_sizes, int n_in,
                              void* d_out, int out_size, void* d_ws, size_t ws_size,
                              hipStream_t stream) {
    const float* A  = (const float*)d_in[0];
    const float* B  = (const float*)d_in[1];
    const float* Wq = (const float*)d_in[2];
    const float* Wk = (const float*)d_in[3];
    const float* Wv = (const float*)d_in[4];
    const float* Wo = (const float*)d_in[5];
    const float* bo = (const float*)d_in[6];
    float* out = (float*)d_out;

    ushort* ws = (ushort*)d_ws;
    const size_t TE = (size_t)NTOK * EMB;  // 1048576 elements
    ushort* wall = ws;                 // 4 * 65536
    ushort* q0  = wall + 4 * 65536;
    ushort* q1  = q0 + TE;
    ushort* k0  = q1 + TE;
    ushort* k1  = k0 + TE;
    ushort* vt0 = k1 + TE;
    ushort* vt1 = vt0 + TE;
    ushort* Opart = vt1 + TE;                       // 8 x 4096 x 256 bf16 = 16 MB
    float* ML = (float*)(Opart + (size_t)8 * 4096 * 256);  // 8 x 4 x 4096 float2 = 1 MB

    cvtW<<<dim3(64, 4), 256, 0, stream>>>(Wq, Wk, Wv, Wo, wall);

    // z 0..2: A -> Q(dir0), K(dir1), V(dir1); z 3..5: B -> Q(dir1), K(dir0), V(dir0)
    qkv_proj<<<dim3(64, 4, 6), 256, 0, stream>>>(A, B, wall, q0, k1, vt1, q1, k0, vt0);

    attn<<<dim3(32, 4, 8), 256, 0, stream>>>(q0, k0, vt0, q1, k1, vt1, Opart, ML);

    out_proj<<<dim3(64, 4, 2), 256, 0, stream>>>(Opart, ML, wall + 3 * 65536, bo, A, B, out);
}